// Round 1
// baseline (167546.851 us; speedup 1.0000x reference)
//
#include <hip/hip_runtime.h>
#include <stdint.h>

#define B 8
#define T 256
#define DIN 6
#define H 200
#define G 800   // 4*H, PyTorch ifgo gate order
#define L 200

// ws layout in 4-byte elements:
//  [0..511]    producer flags (uint32)
//  [512..1023] consumer flags (uint32)
#define OFF_H0    1024
#define OFF_FINAL (OFF_H0 + B*T*H)
#define OFF_RING  (OFF_FINAL + B*T*H)

__device__ __forceinline__ float fsig(float x) {
    return 1.0f / (1.0f + __expf(-x));
}
__device__ __forceinline__ float ftanh(float x) {
    // 1 - 2/(e^{2x}+1): safe at +-inf
    float e = __expf(2.0f * x);
    return 1.0f - 2.0f / (e + 1.0f);
}

__global__ void init_flags(uint32_t* ws) {
    int i = blockIdx.x * 256 + threadIdx.x;
    if (i < 1024) ws[i] = 0u;
}

__global__ void mlp1_kernel(const float* __restrict__ x, const float* __restrict__ W1,
                            const float* __restrict__ b1, float* __restrict__ h0) {
    int idx = blockIdx.x * 256 + threadIdx.x;
    if (idx >= B * T * H) return;
    int j  = idx % H;
    int bt = idx / H;                    // bt = b*T + t
    const float* xr = x  + (size_t)bt * DIN;
    const float* wr = W1 + (size_t)j * DIN;
    float a = b1[j];
#pragma unroll
    for (int k = 0; k < DIN; ++k) a += xr[k] * wr[k];
    h0[idx] = a;                         // [(b*T+t)*H + j]
}

// One workgroup per layer. 256 threads:
//  threads 0..199: matmul, thread = (row-group grp=tid%100 of 8 gate rows, ks=tid/100
//                  selecting Wih*x (ks=0, includes biases) or Whh*h (ks=1))
//  threads 0..199 also do the elementwise gate phase (j = tid).
__global__ __launch_bounds__(256)
void lstm_pipeline(const float* __restrict__ Wih, const float* __restrict__ Whh,
                   const float* __restrict__ bih, const float* __restrict__ bhh,
                   float* ws, int R) {
    const int l   = blockIdx.x;
    const int tid = threadIdx.x;

    float*    h0buf    = ws + OFF_H0;
    float*    finalbuf = ws + OFF_FINAL;
    float*    ring     = ws + OFF_RING;
    uint32_t* prodflag = (uint32_t*)ws;
    uint32_t* consflag = (uint32_t*)ws + 512;

    __shared__ float xs[B][H];
    __shared__ float hs[B][H];
    __shared__ float cs[B][H];
    __shared__ float zs[2][B][G];   // partial gate sums (ks=0 and ks=1)

    for (int i = tid; i < B * H; i += 256) {
        ((float*)hs)[i] = 0.0f;
        ((float*)cs)[i] = 0.0f;
    }

    const float* wih = Wih + (size_t)l * G * H;
    const float* whh = Whh + (size_t)l * G * H;
    const float* bi  = bih + (size_t)l * G;
    const float* bh  = bhh + (size_t)l * G;

    const int grp = tid % 100;
    const int ks  = tid / 100;      // valid when tid < 200

    __syncthreads();

    for (int t = 0; t < T; ++t) {
        // ---- wait for input availability and ring credit ----
        if (tid == 0) {
            if (l > 0) {
                while (__hip_atomic_load(&prodflag[l - 1], __ATOMIC_ACQUIRE,
                                         __HIP_MEMORY_SCOPE_AGENT) < (uint32_t)(t + 1))
                    __builtin_amdgcn_s_sleep(2);
            }
            if (l < L - 1 && t >= R) {
                while (__hip_atomic_load(&consflag[l + 1], __ATOMIC_ACQUIRE,
                                         __HIP_MEMORY_SCOPE_AGENT) < (uint32_t)(t - R + 1))
                    __builtin_amdgcn_s_sleep(2);
            }
        }
        __syncthreads();

        // ---- stage x_t into LDS ----
        if (l == 0) {
            for (int i = tid; i < B * H; i += 256) {
                int b = i / H, k = i % H;
                xs[b][k] = h0buf[(size_t)(b * T + t) * H + k];
            }
        } else {
            const float* src = ring + ((size_t)(l - 1) * R + (size_t)(t % R)) * (B * H);
            for (int i = tid; i < B * H; i += 256) ((float*)xs)[i] = src[i];
        }
        __syncthreads();

        // ring slot consumed -> give credit back to producer
        if (tid == 0 && l > 0)
            __hip_atomic_store(&consflag[l], (uint32_t)(t + 1), __ATOMIC_RELEASE,
                               __HIP_MEMORY_SCOPE_AGENT);

        // ---- gates = [x|h] @ [Wih|Whh]^T + biases ----
        if (tid < 200) {
            const float* Wm = ks ? whh : wih;
            const float (*X)[H] = ks ? hs : xs;
            float acc[8][8];
#pragma unroll
            for (int rr = 0; rr < 8; ++rr) {
                float binit = ks ? 0.0f : (bi[grp * 8 + rr] + bh[grp * 8 + rr]);
#pragma unroll
                for (int b = 0; b < 8; ++b) acc[rr][b] = binit;
            }
            for (int k = 0; k < H; k += 4) {
                float4 w[8];
#pragma unroll
                for (int rr = 0; rr < 8; ++rr)
                    w[rr] = *(const float4*)&Wm[(size_t)(grp * 8 + rr) * H + k];
#pragma unroll
                for (int b = 0; b < 8; ++b) {
                    float4 xv = *(const float4*)&X[b][k];
#pragma unroll
                    for (int rr = 0; rr < 8; ++rr) {
                        acc[rr][b] += w[rr].x * xv.x;
                        acc[rr][b] += w[rr].y * xv.y;
                        acc[rr][b] += w[rr].z * xv.z;
                        acc[rr][b] += w[rr].w * xv.w;
                    }
                }
            }
#pragma unroll
            for (int rr = 0; rr < 8; ++rr)
#pragma unroll
                for (int b = 0; b < 8; ++b)
                    zs[ks][b][grp * 8 + rr] = acc[rr][b];
        }
        __syncthreads();

        // ---- elementwise LSTM cell update, publish h ----
        if (tid < H) {
            const int j = tid;
#pragma unroll
            for (int b = 0; b < 8; ++b) {
                float zi = zs[0][b][j]       + zs[1][b][j];
                float zf = zs[0][b][j + 200] + zs[1][b][j + 200];
                float zg = zs[0][b][j + 400] + zs[1][b][j + 400];
                float zo = zs[0][b][j + 600] + zs[1][b][j + 600];
                float ig = fsig(zi);
                float fg = fsig(zf);
                float gg = ftanh(zg);
                float og = fsig(zo);
                float c  = fg * cs[b][j] + ig * gg;
                cs[b][j] = c;
                float h  = og * ftanh(c);
                hs[b][j] = h;
                if (l < L - 1)
                    ring[(((size_t)l * R + (size_t)(t % R)) * B + b) * H + j] = h;
                else
                    finalbuf[(size_t)(b * T + t) * H + j] = h;
            }
        }
        __threadfence();   // make ring/final writes visible device-wide
        __syncthreads();
        if (tid == 0 && l < L - 1)
            __hip_atomic_store(&prodflag[l], (uint32_t)(t + 1), __ATOMIC_RELEASE,
                               __HIP_MEMORY_SCOPE_AGENT);
    }
}

__global__ __launch_bounds__(64)
void mlp2_kernel(const float* __restrict__ fin, const float* __restrict__ W2a,
                 const float* __restrict__ b2a, const float* __restrict__ W2b,
                 const float* __restrict__ b2b, float* __restrict__ out) {
    const int bt  = blockIdx.x;       // b*T + t
    const int tid = threadIdx.x;
    __shared__ float sx[H];
    __shared__ float sh[50];
    for (int i = tid; i < H; i += 64) sx[i] = fin[(size_t)bt * H + i];
    __syncthreads();
    if (tid < 50) {
        float a = b2a[tid];
        const float* w = W2a + (size_t)tid * H;
        for (int k = 0; k < H; ++k) a += w[k] * sx[k];
        sh[tid] = fmaxf(a, 0.0f);
    }
    __syncthreads();
    if (tid < 24) {
        float a = b2b[tid];
        const float* w = W2b + (size_t)tid * 50;
#pragma unroll
        for (int m = 0; m < 50; ++m) a += w[m] * sh[m];
        out[(size_t)bt * 24 + tid] = a;
    }
}

extern "C" void kernel_launch(void* const* d_in, const int* in_sizes, int n_in,
                              void* d_out, int out_size, void* d_ws, size_t ws_size,
                              hipStream_t stream) {
    const float* x    = (const float*)d_in[0];
    const float* W1   = (const float*)d_in[1];
    const float* b1   = (const float*)d_in[2];
    const float* Wih  = (const float*)d_in[3];
    const float* Whh  = (const float*)d_in[4];
    const float* bihp = (const float*)d_in[5];
    const float* bhhp = (const float*)d_in[6];
    const float* W2a  = (const float*)d_in[7];
    const float* b2a  = (const float*)d_in[8];
    const float* W2b  = (const float*)d_in[9];
    const float* b2b  = (const float*)d_in[10];
    float* out = (float*)d_out;
    float* ws  = (float*)d_ws;

    // ring depth: shrink if workspace is small (R>=1 stays correct, just slower)
    int R = 8;
    while (R > 1 &&
           ((size_t)OFF_RING + (size_t)(L - 1) * R * B * H) * 4ull > ws_size)
        R >>= 1;

    init_flags<<<4, 256, 0, stream>>>((uint32_t*)d_ws);
    mlp1_kernel<<<(B * T * H + 255) / 256, 256, 0, stream>>>(x, W1, b1, ws + OFF_H0);
    lstm_pipeline<<<L, 256, 0, stream>>>(Wih, Whh, bihp, bhhp, ws, R);
    mlp2_kernel<<<B * T, 64, 0, stream>>>(ws + OFF_FINAL, W2a, b2a, W2b, b2b, out);
}

// Round 2
// 43702.496 us; speedup vs baseline: 3.8338x; 3.8338x over previous
//
#include <hip/hip_runtime.h>
#include <hip/hip_bf16.h>
#include <stdint.h>

#define B 8
#define T 256
#define DIN 6
#define H 200
#define G 800   // 4*H, ifgo gate order
#define L 200

// ws layout (float/uint32 elements):
//  [0..4095]     producer flags, one per 16 dwords (cache-line padded)
//  [4096..8191]  consumer flags, one per 16 dwords
#define OFF_H0    8192
#define OFF_FINAL (OFF_H0 + B*T*H)
#define OFF_RING  (OFF_FINAL + B*T*H)
#define PFLAG(l)  ((l) * 16)
#define CFLAG(l)  (4096 + (l) * 16)

__device__ __forceinline__ float fsig(float x) {
    return 1.0f / (1.0f + __expf(-x));
}
__device__ __forceinline__ float ftanh(float x) {
    float e = __expf(2.0f * x);
    return 1.0f - 2.0f / (e + 1.0f);
}

__device__ __forceinline__ uint32_t ld_flag(const uint32_t* p) {
    return __hip_atomic_load(p, __ATOMIC_RELAXED, __HIP_MEMORY_SCOPE_AGENT);
}
__device__ __forceinline__ void st_flag(uint32_t* p, uint32_t v) {
    __hip_atomic_store(p, v, __ATOMIC_RELAXED, __HIP_MEMORY_SCOPE_AGENT);
}
__device__ __forceinline__ void st_data(float* p, float v) {
    __hip_atomic_store((uint32_t*)p, __float_as_uint(v), __ATOMIC_RELAXED,
                       __HIP_MEMORY_SCOPE_AGENT);
}
__device__ __forceinline__ float ld_data(const float* p) {
    return __uint_as_float(__hip_atomic_load((const uint32_t*)p, __ATOMIC_RELAXED,
                                             __HIP_MEMORY_SCOPE_AGENT));
}

__global__ void init_flags(uint32_t* ws) {
    int i = blockIdx.x * 256 + threadIdx.x;
    if (i < 8192) ws[i] = 0u;
}

__global__ void mlp1_kernel(const float* __restrict__ x, const float* __restrict__ W1,
                            const float* __restrict__ b1, float* __restrict__ h0) {
    int idx = blockIdx.x * 256 + threadIdx.x;
    if (idx >= B * T * H) return;
    int j  = idx % H;
    int bt = idx / H;
    const float* xr = x  + (size_t)bt * DIN;
    const float* wr = W1 + (size_t)j * DIN;
    float a = b1[j];
#pragma unroll
    for (int k = 0; k < DIN; ++k) a += xr[k] * wr[k];
    h0[idx] = a;
}

// bf16 relayout: Wc[l][k2][r], k2 in [0,200) = column-pair index over the
// concatenated [x;h] (k2<100 -> Wih cols 2k2,2k2+1 ; k2>=100 -> Whh).
// r in [0,800) gate row. Packed u32 = (bf16(odd col)<<16)|bf16(even col).
__global__ void convert_weights(const float* __restrict__ Wih, const float* __restrict__ Whh,
                                uint32_t* __restrict__ Wc) {
    size_t idx = (size_t)blockIdx.x * 256 + threadIdx.x;  // over L*800*200, k2 fastest
    if (idx >= (size_t)L * 800 * 200) return;
    int    k2 = (int)(idx % 200);
    size_t lr = idx / 200;
    int    r  = (int)(lr % 800);
    int    l  = (int)(lr / 800);
    float w0, w1;
    if (k2 < 100) {
        const float* p = Wih + ((size_t)l * 800 + r) * 200 + 2 * k2;
        w0 = p[0]; w1 = p[1];
    } else {
        const float* p = Whh + ((size_t)l * 800 + r) * 200 + 2 * (k2 - 100);
        w0 = p[0]; w1 = p[1];
    }
    __hip_bfloat16 h0 = __float2bfloat16(w0);
    __hip_bfloat16 h1 = __float2bfloat16(w1);
    uint32_t u0 = *(uint16_t*)&h0, u1 = *(uint16_t*)&h1;
    Wc[((size_t)l * 200 + k2) * 800 + r] = (u1 << 16) | u0;
}

// One workgroup per layer, 256 threads. Thread j<200 owns hidden unit j:
// computes rows j+200*g (g=0..3 -> i,f,g,o) of the gate matmul for all 8
// batches, keeps c in registers, does the cell update locally.
template <bool FAST>
__global__ __launch_bounds__(256)
void lstm_pipeline(const uint32_t* __restrict__ Wc,
                   const float* __restrict__ Wih, const float* __restrict__ Whh,
                   const float* __restrict__ bih, const float* __restrict__ bhh,
                   float* ws, int R) {
    const int l   = blockIdx.x;
    const int tid = threadIdx.x;

    float*    h0buf    = ws + OFF_H0;
    float*    finalbuf = ws + OFF_FINAL;
    float*    ring     = ws + OFF_RING;
    uint32_t* flags    = (uint32_t*)ws;

    __shared__ float xh[B][2 * H];   // [b][0..199]=x_t, [200..399]=h_{t-1}

    for (int i = tid; i < B * 2 * H; i += 256) ((float*)xh)[i] = 0.0f;

    const bool active = tid < H;
    float cs[B];
    float bsum[4];
    if (active) {
#pragma unroll
        for (int g = 0; g < 4; ++g)
            bsum[g] = bih[(size_t)l * G + g * H + tid] + bhh[(size_t)l * G + g * H + tid];
#pragma unroll
        for (int b = 0; b < B; ++b) cs[b] = 0.0f;
    }
    const uint32_t* wl  = FAST ? (Wc + (size_t)l * 200 * 800 + tid) : nullptr;
    const float*    wi0 = Wih + (size_t)l * G * H;
    const float*    wh0 = Whh + (size_t)l * G * H;

    __syncthreads();

    for (int t = 0; t < T; ++t) {
        if (tid == 0) {
            if (l > 0)
                while (ld_flag(&flags[PFLAG(l - 1)]) < (uint32_t)(t + 1))
                    __builtin_amdgcn_s_sleep(2);
            if (l < L - 1 && t >= R)
                while (ld_flag(&flags[CFLAG(l + 1)]) < (uint32_t)(t - R + 1))
                    __builtin_amdgcn_s_sleep(2);
        }
        __syncthreads();

        // stage x_t into xh[.][0..199]
        if (l == 0) {
            for (int i = tid; i < B * H; i += 256) {
                int b = i / H, k = i % H;
                xh[b][k] = h0buf[((size_t)b * T + t) * H + k];
            }
        } else {
            const float* src = ring + ((size_t)(l - 1) * R + (size_t)(t % R)) * (B * H);
            for (int i = tid; i < B * H; i += 256) {
                int b = i / H, k = i % H;
                xh[b][k] = ld_data(src + (size_t)b * H + k);
            }
        }
        __syncthreads();
        if (tid == 0 && l > 0) st_flag(&flags[CFLAG(l)], (uint32_t)(t + 1));

        if (active) {
            float acc[4][B];
#pragma unroll
            for (int g = 0; g < 4; ++g)
#pragma unroll
                for (int b = 0; b < B; ++b) acc[g][b] = (b == 0 || true) ? bsum[g] * (b == 0 ? 1.0f : 1.0f) : 0.0f;
            // (acc[g][b] all start at bsum[g]; bias counted once per row — correct
            //  since each (g,b) is an independent output element of row j+200g.)

            if (FAST) {
#pragma unroll 8
                for (int k2 = 0; k2 < 200; ++k2) {
                    uint32_t wv[4];
#pragma unroll
                    for (int g = 0; g < 4; ++g) wv[g] = wl[(size_t)k2 * 800 + g * 200];
                    float w0[4], w1[4];
#pragma unroll
                    for (int g = 0; g < 4; ++g) {
                        w0[g] = __uint_as_float(wv[g] << 16);
                        w1[g] = __uint_as_float(wv[g] & 0xffff0000u);
                    }
#pragma unroll
                    for (int b = 0; b < B; ++b) {
                        float2 xv = *(const float2*)&xh[b][2 * k2];
#pragma unroll
                        for (int g = 0; g < 4; ++g) {
                            acc[g][b] += w0[g] * xv.x;
                            acc[g][b] += w1[g] * xv.y;
                        }
                    }
                }
            } else {
#pragma unroll 2
                for (int k2 = 0; k2 < 200; ++k2) {
                    float2 wv[4];
                    if (k2 < 100) {
#pragma unroll
                        for (int g = 0; g < 4; ++g)
                            wv[g] = *(const float2*)&wi0[((size_t)(g * 200 + tid)) * 200 + 2 * k2];
                    } else {
#pragma unroll
                        for (int g = 0; g < 4; ++g)
                            wv[g] = *(const float2*)&wh0[((size_t)(g * 200 + tid)) * 200 + 2 * (k2 - 100)];
                    }
#pragma unroll
                    for (int b = 0; b < B; ++b) {
                        float2 xv = *(const float2*)&xh[b][2 * k2];
#pragma unroll
                        for (int g = 0; g < 4; ++g) {
                            acc[g][b] += wv[g].x * xv.x;
                            acc[g][b] += wv[g].y * xv.y;
                        }
                    }
                }
            }

            // cell update + publish h
#pragma unroll
            for (int b = 0; b < B; ++b) {
                float ig = fsig(acc[0][b]);
                float fg = fsig(acc[1][b]);
                float gg = ftanh(acc[2][b]);
                float og = fsig(acc[3][b]);
                float c  = fg * cs[b] + ig * gg;
                cs[b] = c;
                float h = og * ftanh(c);
                xh[b][H + tid] = h;
                if (l < L - 1)
                    st_data(ring + (((size_t)l * R + (size_t)(t % R)) * B + b) * H + tid, h);
                else
                    finalbuf[((size_t)b * T + t) * H + tid] = h;
            }
            asm volatile("s_waitcnt vmcnt(0)" ::: "memory");
        }
        __syncthreads();   // drains vmem in every wave before barrier
        if (tid == 0 && l < L - 1) st_flag(&flags[PFLAG(l)], (uint32_t)(t + 1));
    }
}

__global__ __launch_bounds__(64)
void mlp2_kernel(const float* __restrict__ fin, const float* __restrict__ W2a,
                 const float* __restrict__ b2a, const float* __restrict__ W2b,
                 const float* __restrict__ b2b, float* __restrict__ out) {
    const int bt  = blockIdx.x;   // b*T + t
    const int tid = threadIdx.x;
    __shared__ float sx[H];
    __shared__ float sh[50];
    for (int i = tid; i < H; i += 64) sx[i] = fin[(size_t)bt * H + i];
    __syncthreads();
    if (tid < 50) {
        float a = b2a[tid];
        const float* w = W2a + (size_t)tid * H;
        for (int k = 0; k < H; ++k) a += w[k] * sx[k];
        sh[tid] = fmaxf(a, 0.0f);
    }
    __syncthreads();
    if (tid < 24) {
        float a = b2b[tid];
        const float* w = W2b + (size_t)tid * 50;
#pragma unroll
        for (int m = 0; m < 50; ++m) a += w[m] * sh[m];
        out[(size_t)bt * 24 + tid] = a;
    }
}

extern "C" void kernel_launch(void* const* d_in, const int* in_sizes, int n_in,
                              void* d_out, int out_size, void* d_ws, size_t ws_size,
                              hipStream_t stream) {
    const float* x    = (const float*)d_in[0];
    const float* W1   = (const float*)d_in[1];
    const float* b1   = (const float*)d_in[2];
    const float* Wih  = (const float*)d_in[3];
    const float* Whh  = (const float*)d_in[4];
    const float* bihp = (const float*)d_in[5];
    const float* bhhp = (const float*)d_in[6];
    const float* W2a  = (const float*)d_in[7];
    const float* b2a  = (const float*)d_in[8];
    const float* W2b  = (const float*)d_in[9];
    const float* b2b  = (const float*)d_in[10];
    float* out = (float*)d_out;
    float* ws  = (float*)d_ws;

    const size_t wc_elems = (size_t)L * 200 * 800;   // 32M u32 = 128 MB

    // pick ring depth + mode from available workspace
    int R = 8; bool fast = false; size_t offwc = 0;
    for (;;) {
        size_t ringsz = (size_t)(L - 1) * R * B * H;
        if ((OFF_RING + ringsz + wc_elems) * 4ull <= ws_size) {
            fast = true; offwc = OFF_RING + ringsz; break;
        }
        if (R == 1) break;
        R >>= 1;
    }
    if (!fast) {
        R = 8;
        while (R > 1 && (OFF_RING + (size_t)(L - 1) * R * B * H) * 4ull > ws_size)
            R >>= 1;
    }
    uint32_t* Wc = (uint32_t*)(ws + offwc);

    init_flags<<<32, 256, 0, stream>>>((uint32_t*)d_ws);
    mlp1_kernel<<<(B * T * H + 255) / 256, 256, 0, stream>>>(x, W1, b1, ws + OFF_H0);
    if (fast) {
        convert_weights<<<(int)((wc_elems + 255) / 256), 256, 0, stream>>>(Wih, Whh, Wc);
        lstm_pipeline<true><<<L, 256, 0, stream>>>(Wc, Wih, Whh, bihp, bhhp, ws, R);
    } else {
        lstm_pipeline<false><<<L, 256, 0, stream>>>(Wc, Wih, Whh, bihp, bhhp, ws, R);
    }
    mlp2_kernel<<<B * T, 64, 0, stream>>>(ws + OFF_FINAL, W2a, b2a, W2b, b2b, out);
}

// Round 3
// 16026.921 us; speedup vs baseline: 10.4541x; 2.7268x over previous
//
#include <hip/hip_runtime.h>
#include <hip/hip_bf16.h>
#include <stdint.h>

#define B 8
#define T 256
#define DIN 6
#define H 200
#define G 800   // 4*H, ifgo gate order
#define L 200
#define KBLK 50 // 400 cols / 8 per block

// ws layout (float/uint32 elements):
//  [0..4095]     producer flags, one per 16 dwords (cache-line padded)
//  [4096..8191]  consumer flags
#define OFF_H0    8192
#define OFF_FINAL (OFF_H0 + B*T*H)
#define OFF_RING  (OFF_FINAL + B*T*H)
#define PFLAG(l)  ((l) * 16)
#define CFLAG(l)  (4096 + (l) * 16)

__device__ __forceinline__ float fsig(float x) {
    return 1.0f / (1.0f + __expf(-x));
}
__device__ __forceinline__ float ftanh(float x) {
    float e = __expf(2.0f * x);
    return 1.0f - 2.0f / (e + 1.0f);
}

__device__ __forceinline__ uint32_t ld_flag(const uint32_t* p) {
    return __hip_atomic_load(p, __ATOMIC_RELAXED, __HIP_MEMORY_SCOPE_AGENT);
}
__device__ __forceinline__ void st_flag(uint32_t* p, uint32_t v) {
    __hip_atomic_store(p, v, __ATOMIC_RELAXED, __HIP_MEMORY_SCOPE_AGENT);
}
__device__ __forceinline__ void st_data(float* p, float v) {
    __hip_atomic_store((uint32_t*)p, __float_as_uint(v), __ATOMIC_RELAXED,
                       __HIP_MEMORY_SCOPE_AGENT);
}
__device__ __forceinline__ float ld_data(const float* p) {
    return __uint_as_float(__hip_atomic_load((const uint32_t*)p, __ATOMIC_RELAXED,
                                             __HIP_MEMORY_SCOPE_AGENT));
}

__global__ void init_flags(uint32_t* ws) {
    int i = blockIdx.x * 256 + threadIdx.x;
    if (i < 8192) ws[i] = 0u;
}

__global__ void mlp1_kernel(const float* __restrict__ x, const float* __restrict__ W1,
                            const float* __restrict__ b1, float* __restrict__ h0) {
    int idx = blockIdx.x * 256 + threadIdx.x;
    if (idx >= B * T * H) return;
    int j  = idx % H;
    int bt = idx / H;
    const float* xr = x  + (size_t)bt * DIN;
    const float* wr = W1 + (size_t)j * DIN;
    float a = b1[j];
#pragma unroll
    for (int k = 0; k < DIN; ++k) a += xr[k] * wr[k];
    h0[idx] = a;
}

// Wc[l][kb:50][r:800][k4:4] u32; element = packed bf16 pair for columns
// c=8*kb+2*k4, c+1 of the concatenated [x(0..199) | h(200..399)] input.
__global__ void convert_weights(const float* __restrict__ Wih, const float* __restrict__ Whh,
                                uint32_t* __restrict__ Wc) {
    size_t idx = (size_t)blockIdx.x * 256 + threadIdx.x;   // L*50*800*4, k4 fastest
    if (idx >= (size_t)L * KBLK * G * 4) return;
    int    k4 = (int)(idx & 3);
    size_t q  = idx >> 2;
    int    r  = (int)(q % G);
    size_t q2 = q / G;
    int    kb = (int)(q2 % KBLK);
    int    l  = (int)(q2 / KBLK);
    int    c  = 8 * kb + 2 * k4;
    float w0, w1;
    if (c < 200) {
        const float* p = Wih + ((size_t)l * G + r) * 200 + c;
        w0 = p[0]; w1 = p[1];
    } else {
        const float* p = Whh + ((size_t)l * G + r) * 200 + (c - 200);
        w0 = p[0]; w1 = p[1];
    }
    __hip_bfloat16 h0 = __float2bfloat16(w0);
    __hip_bfloat16 h1 = __float2bfloat16(w1);
    uint32_t u0 = *(uint16_t*)&h0, u1 = *(uint16_t*)&h1;
    Wc[idx] = (u1 << 16) | u0;
}

// One workgroup per layer, 256 threads, 1 block/CU. Thread j<200 owns hidden
// unit j: all 4 gate rows (j+200g) for all 8 batches; c stays in registers.
template <bool FAST>
__global__ __launch_bounds__(256, 1)
void lstm_pipeline(const uint4* __restrict__ WcV,
                   const float* __restrict__ Wih, const float* __restrict__ Whh,
                   const float* __restrict__ bih, const float* __restrict__ bhh,
                   float* ws, int R) {
#pragma clang fp contract(fast)
    const int l   = blockIdx.x;
    const int tid = threadIdx.x;

    float*    h0buf    = ws + OFF_H0;
    float*    finalbuf = ws + OFF_FINAL;
    float*    ring     = ws + OFF_RING;
    uint32_t* flags    = (uint32_t*)ws;

    __shared__ float xh[B][2 * H];   // [b][0..199]=x_t, [200..399]=h_{t-1}

    for (int i = tid; i < B * 2 * H; i += 256) ((float*)xh)[i] = 0.0f;

    const bool active = tid < H;
    float cs[B];
    float bsum[4];
    if (active) {
#pragma unroll
        for (int g = 0; g < 4; ++g)
            bsum[g] = bih[(size_t)l * G + g * H + tid] + bhh[(size_t)l * G + g * H + tid];
#pragma unroll
        for (int b = 0; b < B; ++b) cs[b] = 0.0f;
    }
    // uint4 view: index (l*50 + kb)*800 + g*200 + j
    const uint4* wl  = FAST ? (WcV + (size_t)l * KBLK * G) : nullptr;
    const float* wi0 = Wih + (size_t)l * G * H;
    const float* wh0 = Whh + (size_t)l * G * H;

    __syncthreads();

    for (int t = 0; t < T; ++t) {
        if (tid == 0) {
            if (l > 0)
                while (ld_flag(&flags[PFLAG(l - 1)]) < (uint32_t)(t + 1))
                    __builtin_amdgcn_s_sleep(2);
            if (l < L - 1 && t >= R)
                while (ld_flag(&flags[CFLAG(l + 1)]) < (uint32_t)(t - R + 1))
                    __builtin_amdgcn_s_sleep(2);
        }
        __syncthreads();

        // ---- stage x_t ----
        if (l == 0) {
            for (int i = tid; i < B * H; i += 256) {
                int b = i / H, k = i % H;
                xh[b][k] = h0buf[((size_t)b * T + t) * H + k];
            }
        } else {
            const float* src = ring + ((size_t)(l - 1) * R + (size_t)(t % R)) * (B * H);
            for (int i = tid; i < B * H; i += 256) {
                int b = i / H, k = i % H;
                xh[b][k] = ld_data(src + (size_t)b * H + k);
            }
        }
        __syncthreads();
        if (tid == 0 && l > 0) st_flag(&flags[CFLAG(l)], (uint32_t)(t + 1));

        float2 acc2[4][B];
        if (active) {
#pragma unroll
            for (int g = 0; g < 4; ++g)
#pragma unroll
                for (int b = 0; b < B; ++b) acc2[g][b] = make_float2(bsum[g], 0.0f);

            if (FAST) {
                const float4* xh4 = (const float4*)xh;   // [b*100 + q]
                uint4 wA[4], wB[4];
#pragma unroll
                for (int g = 0; g < 4; ++g) wA[g] = wl[(size_t)0 * G + g * 200 + tid];

#define COMPUTE_KB(kb, wv)                                                      \
                do {                                                            \
                    float2 wf[4][4];                                            \
                    _Pragma("unroll")                                           \
                    for (int g = 0; g < 4; ++g) {                               \
                        uint32_t uu[4] = {wv[g].x, wv[g].y, wv[g].z, wv[g].w};  \
                        _Pragma("unroll")                                       \
                        for (int k4 = 0; k4 < 4; ++k4)                          \
                            wf[g][k4] = make_float2(                            \
                                __uint_as_float(uu[k4] << 16),                  \
                                __uint_as_float(uu[k4] & 0xffff0000u));         \
                    }                                                           \
                    _Pragma("unroll")                                           \
                    for (int b = 0; b < B; ++b) {                               \
                        float4 x0 = xh4[b * 100 + 2 * (kb)];                    \
                        float4 x1 = xh4[b * 100 + 2 * (kb) + 1];                \
                        float2 p0 = make_float2(x0.x, x0.y);                    \
                        float2 p1 = make_float2(x0.z, x0.w);                    \
                        float2 p2 = make_float2(x1.x, x1.y);                    \
                        float2 p3 = make_float2(x1.z, x1.w);                    \
                        _Pragma("unroll")                                       \
                        for (int g = 0; g < 4; ++g) {                           \
                            acc2[g][b] += wf[g][0] * p0;                        \
                            acc2[g][b] += wf[g][1] * p1;                        \
                            acc2[g][b] += wf[g][2] * p2;                        \
                            acc2[g][b] += wf[g][3] * p3;                        \
                        }                                                       \
                    }                                                           \
                } while (0)

                for (int kb = 0; kb < KBLK - 1; kb += 2) {
#pragma unroll
                    for (int g = 0; g < 4; ++g)
                        wB[g] = wl[(size_t)(kb + 1) * G + g * 200 + tid];
                    COMPUTE_KB(kb, wA);
                    if (kb + 2 < KBLK) {
#pragma unroll
                        for (int g = 0; g < 4; ++g)
                            wA[g] = wl[(size_t)(kb + 2) * G + g * 200 + tid];
                    }
                    COMPUTE_KB(kb + 1, wB);
                }
#undef COMPUTE_KB
            } else {
                // f32 fallback (workspace too small for Wc)
                for (int k2 = 0; k2 < 200; ++k2) {
                    float2 wv[4];
                    if (k2 < 100) {
#pragma unroll
                        for (int g = 0; g < 4; ++g)
                            wv[g] = *(const float2*)&wi0[((size_t)(g * 200 + tid)) * 200 + 2 * k2];
                    } else {
#pragma unroll
                        for (int g = 0; g < 4; ++g)
                            wv[g] = *(const float2*)&wh0[((size_t)(g * 200 + tid)) * 200 + 2 * (k2 - 100)];
                    }
#pragma unroll
                    for (int b = 0; b < B; ++b) {
                        float2 xv = *(const float2*)&xh[b][2 * k2];
#pragma unroll
                        for (int g = 0; g < 4; ++g) {
                            acc2[g][b].x += wv[g].x * xv.x;
                            acc2[g][b].y += wv[g].y * xv.y;
                        }
                    }
                }
            }
        }

        // all gate-matmul reads of xh complete before h_t overwrites h_{t-1}
        __syncthreads();

        if (active) {
#pragma unroll
            for (int b = 0; b < B; ++b) {
                float zi = acc2[0][b].x + acc2[0][b].y;
                float zf = acc2[1][b].x + acc2[1][b].y;
                float zg = acc2[2][b].x + acc2[2][b].y;
                float zo = acc2[3][b].x + acc2[3][b].y;
                float ig = fsig(zi);
                float fg = fsig(zf);
                float gg = ftanh(zg);
                float og = fsig(zo);
                float c  = fg * cs[b] + ig * gg;
                cs[b] = c;
                float h = og * ftanh(c);
                xh[b][H + tid] = h;
                if (l < L - 1)
                    st_data(ring + (((size_t)l * R + (size_t)(t % R)) * B + b) * H + tid, h);
                else
                    finalbuf[((size_t)b * T + t) * H + tid] = h;
            }
            asm volatile("s_waitcnt vmcnt(0)" ::: "memory");
        }
        __syncthreads();
        if (tid == 0 && l < L - 1) st_flag(&flags[PFLAG(l)], (uint32_t)(t + 1));
    }
}

__global__ __launch_bounds__(64)
void mlp2_kernel(const float* __restrict__ fin, const float* __restrict__ W2a,
                 const float* __restrict__ b2a, const float* __restrict__ W2b,
                 const float* __restrict__ b2b, float* __restrict__ out) {
    const int bt  = blockIdx.x;   // b*T + t
    const int tid = threadIdx.x;
    __shared__ float sx[H];
    __shared__ float sh[50];
    for (int i = tid; i < H; i += 64) sx[i] = fin[(size_t)bt * H + i];
    __syncthreads();
    if (tid < 50) {
        float a = b2a[tid];
        const float* w = W2a + (size_t)tid * H;
        for (int k = 0; k < H; ++k) a += w[k] * sx[k];
        sh[tid] = fmaxf(a, 0.0f);
    }
    __syncthreads();
    if (tid < 24) {
        float a = b2b[tid];
        const float* w = W2b + (size_t)tid * 50;
#pragma unroll
        for (int m = 0; m < 50; ++m) a += w[m] * sh[m];
        out[(size_t)bt * 24 + tid] = a;
    }
}

extern "C" void kernel_launch(void* const* d_in, const int* in_sizes, int n_in,
                              void* d_out, int out_size, void* d_ws, size_t ws_size,
                              hipStream_t stream) {
    const float* x    = (const float*)d_in[0];
    const float* W1   = (const float*)d_in[1];
    const float* b1   = (const float*)d_in[2];
    const float* Wih  = (const float*)d_in[3];
    const float* Whh  = (const float*)d_in[4];
    const float* bihp = (const float*)d_in[5];
    const float* bhhp = (const float*)d_in[6];
    const float* W2a  = (const float*)d_in[7];
    const float* b2a  = (const float*)d_in[8];
    const float* W2b  = (const float*)d_in[9];
    const float* b2b  = (const float*)d_in[10];
    float* out = (float*)d_out;
    float* ws  = (float*)d_ws;

    const size_t wc_elems = (size_t)L * KBLK * G * 4;   // 32M u32 = 128 MB

    int R = 8; bool fast = false; size_t offwc = 0;
    for (;;) {
        size_t ringsz = (size_t)(L - 1) * R * B * H;
        // align Wc offset to 16B (4 floats)
        size_t o = (OFF_RING + ringsz + 3) & ~(size_t)3;
        if ((o + wc_elems) * 4ull <= ws_size) { fast = true; offwc = o; break; }
        if (R == 1) break;
        R >>= 1;
    }
    if (!fast) {
        R = 8;
        while (R > 1 && (OFF_RING + (size_t)(L - 1) * R * B * H) * 4ull > ws_size)
            R >>= 1;
    }
    uint32_t* Wc = (uint32_t*)(ws + offwc);

    init_flags<<<32, 256, 0, stream>>>((uint32_t*)d_ws);
    mlp1_kernel<<<(B * T * H + 255) / 256, 256, 0, stream>>>(x, W1, b1, ws + OFF_H0);
    if (fast) {
        convert_weights<<<(int)((wc_elems + 255) / 256), 256, 0, stream>>>(Wih, Whh, Wc);
        lstm_pipeline<true><<<L, 256, 0, stream>>>((const uint4*)Wc, Wih, Whh, bihp, bhhp, ws, R);
    } else {
        lstm_pipeline<false><<<L, 256, 0, stream>>>((const uint4*)Wc, Wih, Whh, bihp, bhhp, ws, R);
    }
    mlp2_kernel<<<B * T, 64, 0, stream>>>(ws + OFF_FINAL, W2a, b2a, W2b, b2b, out);
}

// Round 4
// 13662.431 us; speedup vs baseline: 12.2633x; 1.1731x over previous
//
#include <hip/hip_runtime.h>
#include <hip/hip_bf16.h>
#include <stdint.h>

#define B 8
#define T 256
#define DIN 6
#define H 200
#define G 800   // 4*H, ifgo gate order
#define L 200

// weight zones, in 8-column groups (kb8). 50 groups total (400 cols of [x;h]).
#define NKB_REG 12   // cols 0..95    -> registers (12*4 uint4 = 192 VGPR/thread)
#define NKB_LDS 12   // cols 96..191  -> LDS resident (12*800*16 B = 153600 B)
#define NKB_STR 26   // cols 192..399 -> streamed per cell (332.8 KB)

// ws layout (float/uint32 elements):
//  [0..4095]     producer flags, one per 16 dwords
//  [4096..8191]  consumer flags
#define OFF_H0    8192
#define OFF_FINAL (OFF_H0 + B*T*H)
#define OFF_RING  (OFF_FINAL + B*T*H)
#define PFLAG(l)  ((l) * 16)
#define CFLAG(l)  (4096 + (l) * 16)

typedef _Float16 h2v __attribute__((ext_vector_type(2)));

__device__ __forceinline__ float fsig(float x) {
    return 1.0f / (1.0f + __expf(-x));
}
__device__ __forceinline__ float ftanh(float x) {
    float e = __expf(2.0f * x);
    return 1.0f - 2.0f / (e + 1.0f);
}

// packed-f16 dot2 with f32 accumulate
__device__ __forceinline__ float dot2(uint32_t w, uint32_t x, float acc) {
#if __has_builtin(__builtin_amdgcn_fdot2)
    return __builtin_amdgcn_fdot2(__builtin_bit_cast(h2v, w),
                                  __builtin_bit_cast(h2v, x), acc, false);
#else
    h2v a = __builtin_bit_cast(h2v, w);
    h2v b = __builtin_bit_cast(h2v, x);
    return acc + (float)a[0] * (float)b[0] + (float)a[1] * (float)b[1];
#endif
}

__device__ __forceinline__ uint32_t ld_flag(const uint32_t* p) {
    return __hip_atomic_load(p, __ATOMIC_RELAXED, __HIP_MEMORY_SCOPE_AGENT);
}
__device__ __forceinline__ void st_flag(uint32_t* p, uint32_t v) {
    __hip_atomic_store(p, v, __ATOMIC_RELAXED, __HIP_MEMORY_SCOPE_AGENT);
}
__device__ __forceinline__ void st_data(float* p, float v) {
    __hip_atomic_store((uint32_t*)p, __float_as_uint(v), __ATOMIC_RELAXED,
                       __HIP_MEMORY_SCOPE_AGENT);
}
__device__ __forceinline__ float ld_data(const float* p) {
    return __uint_as_float(__hip_atomic_load((const uint32_t*)p, __ATOMIC_RELAXED,
                                             __HIP_MEMORY_SCOPE_AGENT));
}

__global__ void init_flags(uint32_t* ws) {
    int i = blockIdx.x * 256 + threadIdx.x;
    if (i < 8192) ws[i] = 0u;
}

__global__ void mlp1_kernel(const float* __restrict__ x, const float* __restrict__ W1,
                            const float* __restrict__ b1, float* __restrict__ h0) {
    int idx = blockIdx.x * 256 + threadIdx.x;
    if (idx >= B * T * H) return;
    int j  = idx % H;
    int bt = idx / H;
    const float* xr = x  + (size_t)bt * DIN;
    const float* wr = W1 + (size_t)j * DIN;
    float a = b1[j];
#pragma unroll
    for (int k = 0; k < DIN; ++k) a += xr[k] * wr[k];
    h0[idx] = a;
}

// Wc u32 element idx = ((l*50 + kb8)*800 + r)*4 + q : packed f16 pair for
// columns c=kb8*8+2q, c+1 of concatenated [x(0..199)|h(200..399)].
__global__ void convert_weights(const float* __restrict__ Wih, const float* __restrict__ Whh,
                                uint32_t* __restrict__ Wc) {
    size_t idx = (size_t)blockIdx.x * 256 + threadIdx.x;
    if (idx >= (size_t)L * 50 * G * 4) return;
    int    q  = (int)(idx & 3);
    size_t t1 = idx >> 2;
    int    r  = (int)(t1 % G);
    size_t t2 = t1 / G;
    int    kb = (int)(t2 % 50);
    int    l  = (int)(t2 / 50);
    int    c  = kb * 8 + 2 * q;
    float w0, w1;
    if (c < 200) {
        const float* p = Wih + ((size_t)l * G + r) * 200 + c;
        w0 = p[0]; w1 = p[1];
    } else {
        const float* p = Whh + ((size_t)l * G + r) * 200 + (c - 200);
        w0 = p[0]; w1 = p[1];
    }
    _Float16 h0 = (_Float16)w0;
    _Float16 h1 = (_Float16)w1;
    uint16_t u0 = __builtin_bit_cast(uint16_t, h0);
    uint16_t u1 = __builtin_bit_cast(uint16_t, h1);
    Wc[idx] = ((uint32_t)u1 << 16) | u0;
}

// One workgroup per layer, 256 threads, 1 block/CU (160 KB LDS).
// Thread j<200 owns rows j+200g (g=0..3); c stays in registers.
template <bool FAST>
__global__ __launch_bounds__(256, 1)
void lstm_pipeline(const uint4* __restrict__ WcQ,
                   const float* __restrict__ Wih, const float* __restrict__ Whh,
                   const float* __restrict__ bih, const float* __restrict__ bhh,
                   float* ws, int R) {
#pragma clang fp contract(fast)
    const int l   = blockIdx.x;
    const int tid = threadIdx.x;

    float*    h0buf    = ws + OFF_H0;
    float*    finalbuf = ws + OFF_FINAL;
    float*    ring     = ws + OFF_RING;
    uint32_t* flags    = (uint32_t*)ws;

    // 153600 + 6400 = 160000 B <= 163840
    __shared__ __align__(16) uint32_t lds_w[NKB_LDS * G * 4];
    __shared__ __align__(16) uint32_t xhs[B][200];   // packed f16 pairs of [x|h]

    const bool active = tid < H;
    float cs[B];
    float bsum[4];
    if (active) {
#pragma unroll
        for (int g = 0; g < 4; ++g)
            bsum[g] = bih[(size_t)l * G + g * H + tid] + bhh[(size_t)l * G + g * H + tid];
#pragma unroll
        for (int b = 0; b < B; ++b) cs[b] = 0.0f;
    }

    const uint4* wl = WcQ + (size_t)l * 50 * G;   // quad idx: kb8*800 + g*200 + j

    // zero h-part of xhs (and x-part, harmless)
    for (int i = tid; i < B * 200; i += 256) ((uint32_t*)xhs)[i] = 0u;

    uint4 wr[NKB_REG][4];   // register-resident zone
    if (FAST) {
        if (active) {
#pragma unroll
            for (int kb = 0; kb < NKB_REG; ++kb)
#pragma unroll
                for (int g = 0; g < 4; ++g)
                    wr[kb][g] = wl[(size_t)kb * G + g * 200 + tid];
        }
        // LDS-resident zone: groups NKB_REG .. NKB_REG+NKB_LDS-1
        const uint32_t* src = (const uint32_t*)(wl + (size_t)NKB_REG * G);
        for (int i = tid; i < NKB_LDS * G * 4; i += 256) lds_w[i] = src[i];
    }
    __syncthreads();

    _Float16* xh_h = (_Float16*)xhs;          // halves: [b*400 + col]
    const uint4* xq = (const uint4*)xhs;      // quads:  [b*50 + kb8]
    float* xhf = (float*)lds_w;               // fallback-only f32 view [b*400+col]

    for (int t = 0; t < T; ++t) {
        if (tid == 0) {
            if (l > 0)
                while (ld_flag(&flags[PFLAG(l - 1)]) < (uint32_t)(t + 1))
                    __builtin_amdgcn_s_sleep(2);
            if (l < L - 1 && t >= R)
                while (ld_flag(&flags[CFLAG(l + 1)]) < (uint32_t)(t - R + 1))
                    __builtin_amdgcn_s_sleep(2);
        }
        __syncthreads();

        // ---- stage x_t into cols 0..199 ----
        if (l == 0) {
            for (int i = tid; i < B * H; i += 256) {
                int b = i / H, k = i % H;
                float v = h0buf[((size_t)b * T + t) * H + k];
                if (FAST) xh_h[b * 400 + k] = (_Float16)v;
                else      xhf[b * 400 + k] = v;
            }
        } else {
            const float* src = ring + ((size_t)(l - 1) * R + (size_t)(t % R)) * (B * H);
            for (int i = tid; i < B * H; i += 256) {
                int b = i / H, k = i % H;
                float v = ld_data(src + (size_t)b * H + k);
                if (FAST) xh_h[b * 400 + k] = (_Float16)v;
                else      xhf[b * 400 + k] = v;
            }
        }
        __syncthreads();
        if (tid == 0 && l > 0) st_flag(&flags[CFLAG(l)], (uint32_t)(t + 1));

        float acc[4][B];
        if (active) {
#pragma unroll
            for (int g = 0; g < 4; ++g)
#pragma unroll
                for (int b = 0; b < B; ++b) acc[g][b] = bsum[g];

            if (FAST) {
                // stream prologue: 4-deep ring, groups 0..3 of the stream zone
                uint4 u[4][4];
#pragma unroll
                for (int s = 0; s < 4; ++s)
#pragma unroll
                    for (int g = 0; g < 4; ++g)
                        u[s][g] = wl[(size_t)(NKB_REG + NKB_LDS + s) * G + g * 200 + tid];

                // ---- zone 1: register-resident (cols 0..95) ----
#pragma unroll
                for (int kb = 0; kb < NKB_REG; ++kb) {
#pragma unroll
                    for (int b = 0; b < B; ++b) {
                        uint4 xv = xq[b * 50 + kb];
#pragma unroll
                        for (int g = 0; g < 4; ++g) {
                            float a = acc[g][b];
                            a = dot2(wr[kb][g].x, xv.x, a);
                            a = dot2(wr[kb][g].y, xv.y, a);
                            a = dot2(wr[kb][g].z, xv.z, a);
                            a = dot2(wr[kb][g].w, xv.w, a);
                            acc[g][b] = a;
                        }
                    }
                }

                // ---- zone 2: LDS-resident (cols 96..191) ----
                const uint4* lw = (const uint4*)lds_w;
                for (int kb = 0; kb < NKB_LDS; ++kb) {
                    uint4 wv[4];
#pragma unroll
                    for (int g = 0; g < 4; ++g) wv[g] = lw[kb * G + g * 200 + tid];
#pragma unroll
                    for (int b = 0; b < B; ++b) {
                        uint4 xv = xq[b * 50 + NKB_REG + kb];
#pragma unroll
                        for (int g = 0; g < 4; ++g) {
                            float a = acc[g][b];
                            a = dot2(wv[g].x, xv.x, a);
                            a = dot2(wv[g].y, xv.y, a);
                            a = dot2(wv[g].z, xv.z, a);
                            a = dot2(wv[g].w, xv.w, a);
                            acc[g][b] = a;
                        }
                    }
                }

                // ---- zone 3: streamed (cols 192..399), depth-4 ring ----
                for (int s = 0; s < NKB_STR; s += 4) {
#pragma unroll
                    for (int slot = 0; slot < 4; ++slot) {
                        int grp = s + slot;
                        if (grp < NKB_STR) {
                            uint4 wv0 = u[slot][0], wv1 = u[slot][1];
                            uint4 wv2 = u[slot][2], wv3 = u[slot][3];
                            int ng = grp + 4;
                            if (ng < NKB_STR) {
#pragma unroll
                                for (int g = 0; g < 4; ++g)
                                    u[slot][g] = wl[(size_t)(NKB_REG + NKB_LDS + ng) * G + g * 200 + tid];
                            }
#pragma unroll
                            for (int b = 0; b < B; ++b) {
                                uint4 xv = xq[b * 50 + NKB_REG + NKB_LDS + grp];
                                float a0 = acc[0][b], a1 = acc[1][b];
                                float a2 = acc[2][b], a3 = acc[3][b];
                                a0 = dot2(wv0.x, xv.x, a0); a0 = dot2(wv0.y, xv.y, a0);
                                a0 = dot2(wv0.z, xv.z, a0); a0 = dot2(wv0.w, xv.w, a0);
                                a1 = dot2(wv1.x, xv.x, a1); a1 = dot2(wv1.y, xv.y, a1);
                                a1 = dot2(wv1.z, xv.z, a1); a1 = dot2(wv1.w, xv.w, a1);
                                a2 = dot2(wv2.x, xv.x, a2); a2 = dot2(wv2.y, xv.y, a2);
                                a2 = dot2(wv2.z, xv.z, a2); a2 = dot2(wv2.w, xv.w, a2);
                                a3 = dot2(wv3.x, xv.x, a3); a3 = dot2(wv3.y, xv.y, a3);
                                a3 = dot2(wv3.z, xv.z, a3); a3 = dot2(wv3.w, xv.w, a3);
                                acc[0][b] = a0; acc[1][b] = a1;
                                acc[2][b] = a2; acc[3][b] = a3;
                            }
                        }
                    }
                }
            } else {
                // f32 fallback: stream everything (slow but correct)
                const float* wi0 = Wih + (size_t)l * G * H;
                const float* wh0 = Whh + (size_t)l * G * H;
                for (int k2 = 0; k2 < 200; ++k2) {
                    float2 wv[4];
                    if (k2 < 100) {
#pragma unroll
                        for (int g = 0; g < 4; ++g)
                            wv[g] = *(const float2*)&wi0[((size_t)(g * 200 + tid)) * 200 + 2 * k2];
                    } else {
#pragma unroll
                        for (int g = 0; g < 4; ++g)
                            wv[g] = *(const float2*)&wh0[((size_t)(g * 200 + tid)) * 200 + 2 * (k2 - 100)];
                    }
#pragma unroll
                    for (int b = 0; b < B; ++b) {
                        float2 xv = *(const float2*)&xhf[b * 400 + 2 * k2];
#pragma unroll
                        for (int g = 0; g < 4; ++g) {
                            acc[g][b] += wv[g].x * xv.x;
                            acc[g][b] += wv[g].y * xv.y;
                        }
                    }
                }
            }
        }

        // all xh reads complete before h_t overwrites h_{t-1}
        __syncthreads();

        if (active) {
#pragma unroll
            for (int b = 0; b < B; ++b) {
                float ig = fsig(acc[0][b]);
                float fg = fsig(acc[1][b]);
                float gg = ftanh(acc[2][b]);
                float og = fsig(acc[3][b]);
                float c  = fg * cs[b] + ig * gg;
                cs[b] = c;
                float h = og * ftanh(c);
                if (FAST) xh_h[b * 400 + 200 + tid] = (_Float16)h;
                else      xhf[b * 400 + 200 + tid] = h;
                if (l < L - 1)
                    st_data(ring + (((size_t)l * R + (size_t)(t % R)) * B + b) * H + tid, h);
                else
                    finalbuf[((size_t)b * T + t) * H + tid] = h;
            }
            asm volatile("s_waitcnt vmcnt(0)" ::: "memory");
        }
        __syncthreads();
        if (tid == 0 && l < L - 1) st_flag(&flags[PFLAG(l)], (uint32_t)(t + 1));
    }
}

__global__ __launch_bounds__(64)
void mlp2_kernel(const float* __restrict__ fin, const float* __restrict__ W2a,
                 const float* __restrict__ b2a, const float* __restrict__ W2b,
                 const float* __restrict__ b2b, float* __restrict__ out) {
    const int bt  = blockIdx.x;   // b*T + t
    const int tid = threadIdx.x;
    __shared__ float sx[H];
    __shared__ float sh[50];
    for (int i = tid; i < H; i += 64) sx[i] = fin[(size_t)bt * H + i];
    __syncthreads();
    if (tid < 50) {
        float a = b2a[tid];
        const float* w = W2a + (size_t)tid * H;
        for (int k = 0; k < H; ++k) a += w[k] * sx[k];
        sh[tid] = fmaxf(a, 0.0f);
    }
    __syncthreads();
    if (tid < 24) {
        float a = b2b[tid];
        const float* w = W2b + (size_t)tid * 50;
#pragma unroll
        for (int m = 0; m < 50; ++m) a += w[m] * sh[m];
        out[(size_t)bt * 24 + tid] = a;
    }
}

extern "C" void kernel_launch(void* const* d_in, const int* in_sizes, int n_in,
                              void* d_out, int out_size, void* d_ws, size_t ws_size,
                              hipStream_t stream) {
    const float* x    = (const float*)d_in[0];
    const float* W1   = (const float*)d_in[1];
    const float* b1   = (const float*)d_in[2];
    const float* Wih  = (const float*)d_in[3];
    const float* Whh  = (const float*)d_in[4];
    const float* bihp = (const float*)d_in[5];
    const float* bhhp = (const float*)d_in[6];
    const float* W2a  = (const float*)d_in[7];
    const float* b2a  = (const float*)d_in[8];
    const float* W2b  = (const float*)d_in[9];
    const float* b2b  = (const float*)d_in[10];
    float* out = (float*)d_out;
    float* ws  = (float*)d_ws;

    const size_t wc_elems = (size_t)L * 50 * G * 4;   // 32M u32 = 128 MB

    int R = 8; bool fast = false; size_t offwc = 0;
    for (;;) {
        size_t ringsz = (size_t)(L - 1) * R * B * H;
        size_t o = (OFF_RING + ringsz + 3) & ~(size_t)3;   // 16B align
        if ((o + wc_elems) * 4ull <= ws_size) { fast = true; offwc = o; break; }
        if (R == 1) break;
        R >>= 1;
    }
    if (!fast) {
        R = 8;
        while (R > 1 && (OFF_RING + (size_t)(L - 1) * R * B * H) * 4ull > ws_size)
            R >>= 1;
    }
    uint32_t* Wc = (uint32_t*)(ws + offwc);

    init_flags<<<32, 256, 0, stream>>>((uint32_t*)d_ws);
    mlp1_kernel<<<(B * T * H + 255) / 256, 256, 0, stream>>>(x, W1, b1, ws + OFF_H0);
    if (fast) {
        convert_weights<<<(int)((wc_elems + 255) / 256), 256, 0, stream>>>(Wih, Whh, Wc);
        lstm_pipeline<true><<<L, 256, 0, stream>>>((const uint4*)Wc, Wih, Whh, bihp, bhhp, ws, R);
    } else {
        lstm_pipeline<false><<<L, 256, 0, stream>>>((const uint4*)Wc, Wih, Whh, bihp, bhhp, ws, R);
    }
    mlp2_kernel<<<B * T, 64, 0, stream>>>(ws + OFF_FINAL, W2a, b2a, W2b, b2b, out);
}

// Round 5
// 7589.397 us; speedup vs baseline: 22.0764x; 1.8002x over previous
//
#include <hip/hip_runtime.h>
#include <hip/hip_bf16.h>
#include <stdint.h>

#define B 8
#define T 256
#define DIN 6
#define H 200
#define G 800   // 4*H, ifgo gate order
#define L 200

#define NT 13       // N tiles per gate (208 rows, 200 real)
#define KT 13       // K tiles (416 cols, 400 real)
#define NFRAG 169   // NT*KT fragments per (layer,gate)
#define F_REG 65    // kt 0..4  -> registers (260 dwords/lane)
#define F_LDS 26    // kt 5..6  -> LDS resident
// kt 7..12 streamed (78 frags)

// ws layout (float/uint32 elements):
#define OFF_H0    8192
#define OFF_FINAL (OFF_H0 + B*T*H)
#define OFF_RING  (OFF_FINAL + B*T*H)
#define PFLAG(l)  ((l) * 16)
#define CFLAG(l)  (4096 + (l) * 16)

typedef _Float16 half8 __attribute__((ext_vector_type(8)));
typedef float f32x4 __attribute__((ext_vector_type(4)));

__device__ __forceinline__ float fsig(float x) {
    return 1.0f / (1.0f + __expf(-x));
}
__device__ __forceinline__ float ftanh(float x) {
    float e = __expf(2.0f * x);
    return 1.0f - 2.0f / (e + 1.0f);
}

__device__ __forceinline__ uint32_t ld_flag(const uint32_t* p) {
    return __hip_atomic_load(p, __ATOMIC_RELAXED, __HIP_MEMORY_SCOPE_AGENT);
}
__device__ __forceinline__ void st_flag(uint32_t* p, uint32_t v) {
    __hip_atomic_store(p, v, __ATOMIC_RELAXED, __HIP_MEMORY_SCOPE_AGENT);
}
__device__ __forceinline__ void st_data(float* p, float v) {
    __hip_atomic_store((uint32_t*)p, __float_as_uint(v), __ATOMIC_RELAXED,
                       __HIP_MEMORY_SCOPE_AGENT);
}
__device__ __forceinline__ float ld_data(const float* p) {
    return __uint_as_float(__hip_atomic_load((const uint32_t*)p, __ATOMIC_RELAXED,
                                             __HIP_MEMORY_SCOPE_AGENT));
}

__global__ void init_flags(uint32_t* ws) {
    int i = blockIdx.x * 256 + threadIdx.x;
    if (i < 8192) ws[i] = 0u;
}

__global__ void mlp1_kernel(const float* __restrict__ x, const float* __restrict__ W1,
                            const float* __restrict__ b1, float* __restrict__ h0) {
    int idx = blockIdx.x * 256 + threadIdx.x;
    if (idx >= B * T * H) return;
    int j  = idx % H;
    int bt = idx / H;
    const float* xr = x  + (size_t)bt * DIN;
    const float* wr = W1 + (size_t)j * DIN;
    float a = b1[j];
#pragma unroll
    for (int k = 0; k < DIN; ++k) a += xr[k] * wr[k];
    h0[idx] = a;
}

// MFMA fragment layout, f16:
// Wm element ((((l*4+g)*KT + kt)*NT + nt)*64 + lane)*8 + j
//   = Wcat[r][k],  r = g*200 + nt*16 + (lane&15),  k = kt*32 + (lane>>4)*8 + j
//   Wcat[r][k] = k<200 ? Wih[l][r][k] : Whh[l][r][k-200]; 0 outside real range.
__global__ void convert_weights_mfma(const float* __restrict__ Wih,
                                     const float* __restrict__ Whh,
                                     uint16_t* __restrict__ Wm) {
    size_t idx = (size_t)blockIdx.x * 256 + threadIdx.x;
    const size_t TOT = (size_t)L * 4 * NFRAG * 64 * 8;
    if (idx >= TOT) return;
    int j    = (int)(idx & 7);
    int lane = (int)((idx >> 3) & 63);
    size_t r0 = idx >> 9;
    int nt = (int)(r0 % NT); r0 /= NT;
    int kt = (int)(r0 % KT); r0 /= KT;
    int g  = (int)(r0 % 4);
    int l  = (int)(r0 / 4);
    int rl = nt * 16 + (lane & 15);
    int k  = kt * 32 + (lane >> 4) * 8 + j;
    float v = 0.0f;
    if (rl < 200 && k < 400) {
        int r = g * 200 + rl;
        v = (k < 200) ? Wih[((size_t)l * G + r) * 200 + k]
                      : Whh[((size_t)l * G + r) * 200 + (k - 200)];
    }
    _Float16 h = (_Float16)v;
    Wm[idx] = __builtin_bit_cast(uint16_t, h);
}

#define MFMA16(a, b, c) __builtin_amdgcn_mfma_f32_16x16x32_f16((a), (b), (c), 0, 0, 0)

// One workgroup per layer, 256 threads = 4 waves, wave w = gate w.
template <bool FAST>
__global__ __launch_bounds__(256, 1)
void lstm_pipeline(const uint4* __restrict__ Wm,
                   const float* __restrict__ Wih, const float* __restrict__ Whh,
                   const float* __restrict__ bih, const float* __restrict__ bhh,
                   float* ws, int R) {
#pragma clang fp contract(fast)
    const int l    = blockIdx.x;
    const int tid  = threadIdx.x;
    const int wv   = tid >> 6;      // gate index
    const int lane = tid & 63;

    float*    h0buf    = ws + OFF_H0;
    float*    finalbuf = ws + OFF_FINAL;
    float*    ring     = ws + OFF_RING;
    uint32_t* flags    = (uint32_t*)ws;

    __shared__ __align__(16) _Float16 xh[16 * 416];        // [m][k] A-matrix, 13312 B
    __shared__ __align__(16) float    zl[4 * 8 * 208];     // [g][b][nj], 26624 B
    __shared__ __align__(16) uint4    wlds[4 * F_LDS * 64];// LDS weight zone, 106496 B

    // zero xh once: covers pad rows 8..15 and pad cols 400..415
    for (int i = tid; i < 832; i += 256)
        ((uint4*)xh)[i] = make_uint4(0u, 0u, 0u, 0u);

    const bool actj = tid < H;
    float cs[B];
    float bs[4];
    if (actj) {
#pragma unroll
        for (int g = 0; g < 4; ++g)
            bs[g] = bih[(size_t)l * G + g * H + tid] + bhh[(size_t)l * G + g * H + tid];
#pragma unroll
        for (int b = 0; b < B; ++b) cs[b] = 0.0f;
    }

    const uint4* wq = Wm + (size_t)(l * 4 + wv) * NFRAG * 64;

    uint4 wreg[F_REG];
    if (FAST) {
#pragma unroll
        for (int f = 0; f < F_REG; ++f) wreg[f] = wq[f * 64 + lane];
        for (int i = 0; i < F_LDS; ++i)
            wlds[(wv * F_LDS + i) * 64 + lane] = wq[(F_REG + i) * 64 + lane];
    }
    float* xhf = (float*)wlds;   // fallback-only f32 view [b*416 + col]
    __syncthreads();

    for (int t = 0; t < T; ++t) {
        if (tid == 0) {
            if (l > 0)
                while (ld_flag(&flags[PFLAG(l - 1)]) < (uint32_t)(t + 1))
                    __builtin_amdgcn_s_sleep(2);
            if (l < L - 1 && t >= R)
                while (ld_flag(&flags[CFLAG(l + 1)]) < (uint32_t)(t - R + 1))
                    __builtin_amdgcn_s_sleep(2);
        }
        __syncthreads();

        // ---- stage x_t into cols 0..199 ----
        if (l == 0) {
            for (int i = tid; i < B * H; i += 256) {
                int b = i / H, k = i % H;
                float v = h0buf[((size_t)b * T + t) * H + k];
                if (FAST) xh[b * 416 + k] = (_Float16)v;
                else      xhf[b * 416 + k] = v;
            }
        } else {
            const float* src = ring + ((size_t)(l - 1) * R + (size_t)(t % R)) * (B * H);
            for (int i = tid; i < B * H; i += 256) {
                int b = i / H, k = i % H;
                float v = ld_data(src + (size_t)b * H + k);
                if (FAST) xh[b * 416 + k] = (_Float16)v;
                else      xhf[b * 416 + k] = v;
            }
        }
        __syncthreads();
        if (tid == 0 && l > 0) st_flag(&flags[CFLAG(l)], (uint32_t)(t + 1));

        if (FAST) {
            f32x4 acc[NT];
#pragma unroll
            for (int nt = 0; nt < NT; ++nt) acc[nt] = (f32x4){0.f, 0.f, 0.f, 0.f};

            // stream prologue: kt 7, 8
            uint4 s0[NT], s1[NT];
#pragma unroll
            for (int n = 0; n < NT; ++n) s0[n] = wq[(F_REG + F_LDS + 0 * NT + n) * 64 + lane];
#pragma unroll
            for (int n = 0; n < NT; ++n) s1[n] = wq[(F_REG + F_LDS + 1 * NT + n) * 64 + lane];

#define LDA(kt) (*(const half8*)&xh[(lane & 15) * 416 + (kt) * 32 + (lane >> 4) * 8])

            // zone 1: registers, kt 0..4
#pragma unroll
            for (int kt = 0; kt < 5; ++kt) {
                half8 a = LDA(kt);
#pragma unroll
                for (int nt = 0; nt < NT; ++nt)
                    acc[nt] = MFMA16(a, __builtin_bit_cast(half8, wreg[kt * NT + nt]), acc[nt]);
            }
            // zone 2: LDS, kt 5..6
#pragma unroll
            for (int kt = 5; kt < 7; ++kt) {
                half8 a = LDA(kt);
#pragma unroll
                for (int nt = 0; nt < NT; ++nt) {
                    uint4 w = wlds[(wv * F_LDS + (kt - 5) * NT + nt) * 64 + lane];
                    acc[nt] = MFMA16(a, __builtin_bit_cast(half8, w), acc[nt]);
                }
            }
            // zone 3: streamed, kt 7..12, depth-2 group ring
#define STREAM_STEP(kt, S, REFILL_KT)                                           \
            do {                                                                \
                half8 a = LDA(kt);                                              \
                _Pragma("unroll")                                               \
                for (int nt = 0; nt < NT; ++nt)                                 \
                    acc[nt] = MFMA16(a, __builtin_bit_cast(half8, S[nt]), acc[nt]); \
                if ((REFILL_KT) < 13) {                                         \
                    _Pragma("unroll")                                           \
                    for (int n = 0; n < NT; ++n)                                \
                        S[n] = wq[(F_REG + F_LDS + ((REFILL_KT) - 7) * NT + n) * 64 + lane]; \
                }                                                               \
            } while (0)

            STREAM_STEP(7,  s0, 9);
            STREAM_STEP(8,  s1, 10);
            STREAM_STEP(9,  s0, 11);
            STREAM_STEP(10, s1, 12);
            STREAM_STEP(11, s0, 13);
            STREAM_STEP(12, s1, 13);
#undef STREAM_STEP
#undef LDA

            // write gate pre-activations: D row m=(lane>>4)*4+reg (batch), col n=lane&15
            if ((lane >> 4) < 2) {
#pragma unroll
                for (int nt = 0; nt < NT; ++nt) {
                    int nj = nt * 16 + (lane & 15);
#pragma unroll
                    for (int r = 0; r < 4; ++r) {
                        int b = (lane >> 4) * 4 + r;
                        zl[(wv * 8 + b) * 208 + nj] = acc[nt][r];
                    }
                }
            }
        } else {
            // f32 fallback: stream raw weights (slow but correct)
            if (actj) {
                const float* wi0 = Wih + (size_t)l * G * H;
                const float* wh0 = Whh + (size_t)l * G * H;
                float acc[4][B];
#pragma unroll
                for (int g = 0; g < 4; ++g)
#pragma unroll
                    for (int b = 0; b < B; ++b) acc[g][b] = 0.0f;
                for (int k2 = 0; k2 < 200; ++k2) {
                    float2 wvv[4];
                    if (k2 < 100) {
#pragma unroll
                        for (int g = 0; g < 4; ++g)
                            wvv[g] = *(const float2*)&wi0[((size_t)(g * 200 + tid)) * 200 + 2 * k2];
                    } else {
#pragma unroll
                        for (int g = 0; g < 4; ++g)
                            wvv[g] = *(const float2*)&wh0[((size_t)(g * 200 + tid)) * 200 + 2 * (k2 - 100)];
                    }
#pragma unroll
                    for (int b = 0; b < B; ++b) {
                        float2 xv = *(const float2*)&xhf[b * 416 + 2 * k2];
#pragma unroll
                        for (int g = 0; g < 4; ++g) {
                            acc[g][b] += wvv[g].x * xv.x;
                            acc[g][b] += wvv[g].y * xv.y;
                        }
                    }
                }
#pragma unroll
                for (int g = 0; g < 4; ++g)
#pragma unroll
                    for (int b = 0; b < B; ++b)
                        zl[(g * 8 + b) * 208 + tid] = acc[g][b];
            }
        }
        __syncthreads();   // z complete; also guards xh h-part overwrite below

        if (actj) {
#pragma unroll
            for (int b = 0; b < B; ++b) {
                float zi = zl[(0 * 8 + b) * 208 + tid] + bs[0];
                float zf = zl[(1 * 8 + b) * 208 + tid] + bs[1];
                float zg = zl[(2 * 8 + b) * 208 + tid] + bs[2];
                float zo = zl[(3 * 8 + b) * 208 + tid] + bs[3];
                float ig = fsig(zi);
                float fg = fsig(zf);
                float gg = ftanh(zg);
                float og = fsig(zo);
                float c  = fg * cs[b] + ig * gg;
                cs[b] = c;
                float h = og * ftanh(c);
                if (FAST) xh[b * 416 + 200 + tid] = (_Float16)h;
                else      xhf[b * 416 + 200 + tid] = h;
                if (l < L - 1)
                    st_data(ring + (((size_t)l * R + (size_t)(t % R)) * B + b) * H + tid, h);
                else
                    finalbuf[((size_t)b * T + t) * H + tid] = h;
            }
            asm volatile("s_waitcnt vmcnt(0)" ::: "memory");
        }
        __syncthreads();
        if (tid == 0 && l < L - 1) st_flag(&flags[PFLAG(l)], (uint32_t)(t + 1));
    }
}

__global__ __launch_bounds__(64)
void mlp2_kernel(const float* __restrict__ fin, const float* __restrict__ W2a,
                 const float* __restrict__ b2a, const float* __restrict__ W2b,
                 const float* __restrict__ b2b, float* __restrict__ out) {
    const int bt  = blockIdx.x;   // b*T + t
    const int tid = threadIdx.x;
    __shared__ float sx[H];
    __shared__ float sh[50];
    for (int i = tid; i < H; i += 64) sx[i] = fin[(size_t)bt * H + i];
    __syncthreads();
    if (tid < 50) {
        float a = b2a[tid];
        const float* w = W2a + (size_t)tid * H;
        for (int k = 0; k < H; ++k) a += w[k] * sx[k];
        sh[tid] = fmaxf(a, 0.0f);
    }
    __syncthreads();
    if (tid < 24) {
        float a = b2b[tid];
        const float* w = W2b + (size_t)tid * 50;
#pragma unroll
        for (int m = 0; m < 50; ++m) a += w[m] * sh[m];
        out[(size_t)bt * 24 + tid] = a;
    }
}

extern "C" void kernel_launch(void* const* d_in, const int* in_sizes, int n_in,
                              void* d_out, int out_size, void* d_ws, size_t ws_size,
                              hipStream_t stream) {
    const float* x    = (const float*)d_in[0];
    const float* W1   = (const float*)d_in[1];
    const float* b1   = (const float*)d_in[2];
    const float* Wih  = (const float*)d_in[3];
    const float* Whh  = (const float*)d_in[4];
    const float* bihp = (const float*)d_in[5];
    const float* bhhp = (const float*)d_in[6];
    const float* W2a  = (const float*)d_in[7];
    const float* b2a  = (const float*)d_in[8];
    const float* W2b  = (const float*)d_in[9];
    const float* b2b  = (const float*)d_in[10];
    float* out = (float*)d_out;
    float* ws  = (float*)d_ws;

    const size_t wm_halves = (size_t)L * 4 * NFRAG * 64 * 8;   // 69.2M f16
    const size_t wm_u32    = wm_halves / 2;                    // 138.4 MB

    int R = 8; bool fast = false; size_t offwm = 0;
    for (;;) {
        size_t ringsz = (size_t)(L - 1) * R * B * H;
        size_t o = (OFF_RING + ringsz + 3) & ~(size_t)3;   // 16B align
        if ((o + wm_u32) * 4ull <= ws_size) { fast = true; offwm = o; break; }
        if (R == 1) break;
        R >>= 1;
    }
    if (!fast) {
        R = 8;
        while (R > 1 && (OFF_RING + (size_t)(L - 1) * R * B * H) * 4ull > ws_size)
            R >>= 1;
    }
    uint4* Wm = (uint4*)(ws + offwm);

    init_flags<<<32, 256, 0, stream>>>((uint32_t*)d_ws);
    mlp1_kernel<<<(B * T * H + 255) / 256, 256, 0, stream>>>(x, W1, b1, ws + OFF_H0);
    if (fast) {
        convert_weights_mfma<<<(int)((wm_halves + 255) / 256), 256, 0, stream>>>(
            Wih, Whh, (uint16_t*)Wm);
        lstm_pipeline<true><<<L, 256, 0, stream>>>(Wm, Wih, Whh, bihp, bhhp, ws, R);
    } else {
        lstm_pipeline<false><<<L, 256, 0, stream>>>(Wm, Wih, Whh, bihp, bhhp, ws, R);
    }
    mlp2_kernel<<<B * T, 64, 0, stream>>>(ws + OFF_FINAL, W2a, b2a, W2b, b2b, out);
}